// Round 1
// baseline (4532.391 us; speedup 1.0000x reference)
//
#include <hip/hip_runtime.h>

// Problem constants (from reference): B=8, T=12, N=10000, D=16, E=160000
#define NB_BT 96            // B*T
#define NN    10000         // nodes
#define DD    16            // feature dim
#define NE    160000        // edges
#define Q_PER_EDGE 384      // (B*T*D)/4 float4 slots per edge

#define NEG_INF_BITS 0xFF800000u

__device__ __forceinline__ void atomic_max_float(float* addr, float v) {
    v = v + 0.0f; // canonicalize -0.0 -> +0.0
    if (v >= 0.0f) {
        atomicMax((int*)addr, __float_as_int(v));
    } else {
        atomicMin((unsigned int*)addr, __float_as_uint(v));
    }
}

__global__ void init_neg_inf(uint4* __restrict__ out, int n4) {
    int i = blockIdx.x * blockDim.x + threadIdx.x;
    if (i < n4) {
        uint4 v;
        v.x = v.y = v.z = v.w = NEG_INF_BITS;
        out[i] = v;
    }
}

__global__ void edge_max(const float* __restrict__ V,
                         const int* __restrict__ src,
                         const int* __restrict__ dst,
                         const float* __restrict__ w,
                         float* __restrict__ out) {
    int idx = blockIdx.x * blockDim.x + threadIdx.x;
    if (idx >= NE * Q_PER_EDGE) return;
    int e = idx / Q_PER_EDGE;
    int q = idx - e * Q_PER_EDGE;
    int s  = src[e];
    int t  = dst[e];
    float we = w[e];
    int bt = q >> 2;          // 0..95
    int d4 = (q & 3) << 2;    // 0,4,8,12

    const float4 v = *reinterpret_cast<const float4*>(V + (bt * NN + s) * DD + d4);
    float* o = out + (bt * NN + t) * DD + d4;
    atomic_max_float(o + 0, v.x * we);
    atomic_max_float(o + 1, v.y * we);
    atomic_max_float(o + 2, v.z * we);
    atomic_max_float(o + 3, v.w * we);
}

__global__ void finalize_zero(uint4* __restrict__ out, int n4) {
    int i = blockIdx.x * blockDim.x + threadIdx.x;
    if (i < n4) {
        uint4 v = out[i];
        if (v.x == NEG_INF_BITS) v.x = 0u;
        if (v.y == NEG_INF_BITS) v.y = 0u;
        if (v.z == NEG_INF_BITS) v.z = 0u;
        if (v.w == NEG_INF_BITS) v.w = 0u;
        out[i] = v;
    }
}

extern "C" void kernel_launch(void* const* d_in, const int* in_sizes, int n_in,
                              void* d_out, int out_size, void* d_ws, size_t ws_size,
                              hipStream_t stream) {
    const float* V   = (const float*)d_in[0];
    const int*   src = (const int*)d_in[1];
    const int*   dst = (const int*)d_in[2];
    const float* w   = (const float*)d_in[3];
    // d_in[4] (V_in) and d_in[5] (adp) are unused by the reference computation.
    float* out = (float*)d_out;

    int n  = out_size;      // 15,360,000
    int n4 = n / 4;         // 3,840,000

    init_neg_inf<<<(n4 + 255) / 256, 256, 0, stream>>>((uint4*)out, n4);

    long total = (long)NE * Q_PER_EDGE;   // 61,440,000
    edge_max<<<(int)((total + 255) / 256), 256, 0, stream>>>(V, src, dst, w, out);

    finalize_zero<<<(n4 + 255) / 256, 256, 0, stream>>>((uint4*)out, n4);
}

// Round 2
// 331.772 us; speedup vs baseline: 13.6612x; 13.6612x over previous
//
#include <hip/hip_runtime.h>

// Problem constants: B=8, T=12 (BT=96), N=10000, D=16, E=160000
#define NN  10000
#define NE  160000
#define NBT 96
#define DD  16
#define SCAN_THREADS 256
#define CHUNK ((NN + SCAN_THREADS - 1) / SCAN_THREADS)   // 40

#define NEG_INF_BITS 0xFF800000u

// ---------------- CSR build ----------------

__global__ void k_zero(int* __restrict__ counts) {
    int i = blockIdx.x * blockDim.x + threadIdx.x;
    if (i < NN) counts[i] = 0;
}

__global__ void k_hist(const int* __restrict__ dst, int* __restrict__ counts) {
    int e = blockIdx.x * blockDim.x + threadIdx.x;
    if (e < NE) atomicAdd(&counts[dst[e]], 1);
}

// Single-block exclusive scan over counts[0..NN) -> offsets[0..NN], cursor copy.
__global__ __launch_bounds__(SCAN_THREADS) void k_scan(const int* __restrict__ counts,
                                                       int* __restrict__ offsets,
                                                       int* __restrict__ cursor) {
    __shared__ int part[SCAN_THREADS];
    int tid = threadIdx.x;
    int begin = tid * CHUNK;
    int end   = min(begin + CHUNK, NN);
    int s = 0;
    for (int i = begin; i < end; ++i) s += counts[i];
    part[tid] = s;
    __syncthreads();
    // Hillis-Steele inclusive scan
    for (int off = 1; off < SCAN_THREADS; off <<= 1) {
        int v = (tid >= off) ? part[tid - off] : 0;
        __syncthreads();
        part[tid] += v;
        __syncthreads();
    }
    int run = (tid == 0) ? 0 : part[tid - 1];  // exclusive base
    for (int i = begin; i < end; ++i) {
        offsets[i] = run;
        cursor[i]  = run;
        run += counts[i];
    }
    if (tid == SCAN_THREADS - 1) offsets[NN] = part[SCAN_THREADS - 1]; // == NE
}

__global__ void k_scatter(const int* __restrict__ src, const int* __restrict__ dst,
                          const float* __restrict__ w,
                          int* __restrict__ cursor,
                          int* __restrict__ esrc, float* __restrict__ ew) {
    int e = blockIdx.x * blockDim.x + threadIdx.x;
    if (e >= NE) return;
    int d = dst[e];
    int pos = atomicAdd(&cursor[d], 1);
    esrc[pos] = src[e];
    ew[pos]   = w[e];
}

// ---------------- main gather-max ----------------
// One block per node; 384 threads = (bt 0..95) x (d4 slot 0..3).
__global__ __launch_bounds__(384) void k_main(const float* __restrict__ V,
                                              const int* __restrict__ offsets,
                                              const int* __restrict__ esrc,
                                              const float* __restrict__ ew,
                                              float* __restrict__ out) {
    int n   = blockIdx.x;
    int tid = threadIdx.x;
    int bt  = tid >> 2;
    int d4  = (tid & 3) << 2;

    __shared__ int   s_src[384];
    __shared__ float s_w[384];

    int beg = offsets[n];
    int endo = offsets[n + 1];

    float4 acc;
    acc.x = acc.y = acc.z = acc.w = -__builtin_huge_valf();

    for (int base = beg; base < endo; base += 384) {
        int m = min(384, endo - base);
        if (tid < m) {
            s_src[tid] = esrc[base + tid];
            s_w[tid]   = ew[base + tid];
        }
        __syncthreads();
        for (int j = 0; j < m; ++j) {
            int   s  = s_src[j];
            float we = s_w[j];
            const float4 v = *reinterpret_cast<const float4*>(V + ((long)bt * NN + s) * DD + d4);
            acc.x = fmaxf(acc.x, v.x * we);
            acc.y = fmaxf(acc.y, v.y * we);
            acc.z = fmaxf(acc.z, v.z * we);
            acc.w = fmaxf(acc.w, v.w * we);
        }
        __syncthreads();
    }

    const float ninf = -__builtin_huge_valf();
    float4 r;
    r.x = (acc.x == ninf) ? 0.0f : acc.x;
    r.y = (acc.y == ninf) ? 0.0f : acc.y;
    r.z = (acc.z == ninf) ? 0.0f : acc.z;
    r.w = (acc.w == ninf) ? 0.0f : acc.w;
    *reinterpret_cast<float4*>(out + ((long)bt * NN + n) * DD + d4) = r;
}

// ---------------- fallback (round-0 atomic path, used only if ws too small) ----

__device__ __forceinline__ void atomic_max_float(float* addr, float v) {
    v = v + 0.0f;
    if (v >= 0.0f) atomicMax((int*)addr, __float_as_int(v));
    else           atomicMin((unsigned int*)addr, __float_as_uint(v));
}

__global__ void init_neg_inf(uint4* __restrict__ out, int n4) {
    int i = blockIdx.x * blockDim.x + threadIdx.x;
    if (i < n4) { uint4 v; v.x = v.y = v.z = v.w = NEG_INF_BITS; out[i] = v; }
}

__global__ void edge_max(const float* __restrict__ V, const int* __restrict__ src,
                         const int* __restrict__ dst, const float* __restrict__ w,
                         float* __restrict__ out) {
    int idx = blockIdx.x * blockDim.x + threadIdx.x;
    if (idx >= NE * 384) return;
    int e = idx / 384;
    int q = idx - e * 384;
    int s = src[e], t = dst[e];
    float we = w[e];
    int bt = q >> 2, d4 = (q & 3) << 2;
    const float4 v = *reinterpret_cast<const float4*>(V + (bt * NN + s) * DD + d4);
    float* o = out + (bt * NN + t) * DD + d4;
    atomic_max_float(o + 0, v.x * we);
    atomic_max_float(o + 1, v.y * we);
    atomic_max_float(o + 2, v.z * we);
    atomic_max_float(o + 3, v.w * we);
}

__global__ void finalize_zero(uint4* __restrict__ out, int n4) {
    int i = blockIdx.x * blockDim.x + threadIdx.x;
    if (i < n4) {
        uint4 v = out[i];
        if (v.x == NEG_INF_BITS) v.x = 0u;
        if (v.y == NEG_INF_BITS) v.y = 0u;
        if (v.z == NEG_INF_BITS) v.z = 0u;
        if (v.w == NEG_INF_BITS) v.w = 0u;
        out[i] = v;
    }
}

// ---------------- launch ----------------

extern "C" void kernel_launch(void* const* d_in, const int* in_sizes, int n_in,
                              void* d_out, int out_size, void* d_ws, size_t ws_size,
                              hipStream_t stream) {
    const float* V   = (const float*)d_in[0];
    const int*   src = (const int*)d_in[1];
    const int*   dst = (const int*)d_in[2];
    const float* w   = (const float*)d_in[3];
    float* out = (float*)d_out;

    // ws layout (ints/floats, 4B each):
    // [0, NN)                       counts
    // [NN, 2NN+1)                   offsets
    // [2NN+1, 3NN+1)                cursor
    // [3NN+1, 3NN+1+NE)             esrc
    // [3NN+1+NE, 3NN+1+2NE)        ew
    size_t needed = (size_t)(3 * NN + 1 + 2 * NE) * 4;
    if (ws_size < needed) {
        // fallback: atomic path
        int n4 = out_size / 4;
        init_neg_inf<<<(n4 + 255) / 256, 256, 0, stream>>>((uint4*)out, n4);
        long total = (long)NE * 384;
        edge_max<<<(int)((total + 255) / 256), 256, 0, stream>>>(V, src, dst, w, out);
        finalize_zero<<<(n4 + 255) / 256, 256, 0, stream>>>((uint4*)out, n4);
        return;
    }

    int* ws_i = (int*)d_ws;
    int*   counts  = ws_i;
    int*   offsets = ws_i + NN;
    int*   cursor  = ws_i + 2 * NN + 1;
    int*   esrc    = ws_i + 3 * NN + 1;
    float* ew      = (float*)(ws_i + 3 * NN + 1 + NE);

    k_zero<<<(NN + 255) / 256, 256, 0, stream>>>(counts);
    k_hist<<<(NE + 255) / 256, 256, 0, stream>>>(dst, counts);
    k_scan<<<1, SCAN_THREADS, 0, stream>>>(counts, offsets, cursor);
    k_scatter<<<(NE + 255) / 256, 256, 0, stream>>>(src, dst, w, cursor, esrc, ew);
    k_main<<<NN, 384, 0, stream>>>(V, offsets, esrc, ew, out);
}

// Round 3
// 331.410 us; speedup vs baseline: 13.6761x; 1.0011x over previous
//
#include <hip/hip_runtime.h>

// Problem constants: B=8, T=12 (BT=96), N=10000, D=16, E=160000
#define NN  10000
#define NE  160000
#define NBT 96
#define DD  16
#define SCAN_THREADS 256
#define CHUNK ((NN + SCAN_THREADS - 1) / SCAN_THREADS)   // 40

// ---------------- CSR build ----------------

__global__ void k_zero(int* __restrict__ counts) {
    int i = blockIdx.x * blockDim.x + threadIdx.x;
    if (i < NN) counts[i] = 0;
}

__global__ void k_hist(const int* __restrict__ dst, int* __restrict__ counts) {
    int e = blockIdx.x * blockDim.x + threadIdx.x;
    if (e < NE) atomicAdd(&counts[dst[e]], 1);
}

__global__ __launch_bounds__(SCAN_THREADS) void k_scan(const int* __restrict__ counts,
                                                       int* __restrict__ offsets,
                                                       int* __restrict__ cursor) {
    __shared__ int part[SCAN_THREADS];
    int tid = threadIdx.x;
    int begin = tid * CHUNK;
    int end   = min(begin + CHUNK, NN);
    int s = 0;
    for (int i = begin; i < end; ++i) s += counts[i];
    part[tid] = s;
    __syncthreads();
    for (int off = 1; off < SCAN_THREADS; off <<= 1) {
        int v = (tid >= off) ? part[tid - off] : 0;
        __syncthreads();
        part[tid] += v;
        __syncthreads();
    }
    int run = (tid == 0) ? 0 : part[tid - 1];
    for (int i = begin; i < end; ++i) {
        offsets[i] = run;
        cursor[i]  = run;
        run += counts[i];
    }
    if (tid == SCAN_THREADS - 1) offsets[NN] = part[SCAN_THREADS - 1];
}

__global__ void k_scatter(const int* __restrict__ src, const int* __restrict__ dst,
                          const float* __restrict__ w,
                          int* __restrict__ cursor,
                          int* __restrict__ esrc, float* __restrict__ ew) {
    int e = blockIdx.x * blockDim.x + threadIdx.x;
    if (e >= NE) return;
    int d = dst[e];
    int pos = atomicAdd(&cursor[d], 1);
    esrc[pos] = src[e];
    ew[pos]   = w[e];
}

// ---------------- main gather-max ----------------
// One block per node; 384 threads = (bt 0..95) x (d4 slot 0..3).
// Edge loop unrolled x8: all 8 independent float4 gathers issued before any fmax.
__global__ __launch_bounds__(384) void k_main(const float* __restrict__ V,
                                              const int* __restrict__ offsets,
                                              const int* __restrict__ esrc,
                                              const float* __restrict__ ew,
                                              float* __restrict__ out) {
    int n   = blockIdx.x;
    int tid = threadIdx.x;
    int bt  = tid >> 2;
    int d4  = (tid & 3) << 2;

    __shared__ int   s_src[384];
    __shared__ float s_w[384];

    int beg  = offsets[n];
    int endo = offsets[n + 1];

    const float* Vbt = V + (long)bt * (NN * DD) + d4;

    float4 acc;
    acc.x = acc.y = acc.z = acc.w = -__builtin_huge_valf();

    for (int base = beg; base < endo; base += 384) {
        int m = min(384, endo - base);
        if (tid < m) {
            s_src[tid] = esrc[base + tid];
            s_w[tid]   = ew[base + tid];
        }
        __syncthreads();

        int j = 0;
        for (; j + 8 <= m; j += 8) {
            float4 v[8];
            float  we[8];
            #pragma unroll
            for (int u = 0; u < 8; ++u) {
                int s = s_src[j + u];
                we[u] = s_w[j + u];
                v[u]  = *reinterpret_cast<const float4*>(Vbt + s * DD);
            }
            #pragma unroll
            for (int u = 0; u < 8; ++u) {
                acc.x = fmaxf(acc.x, v[u].x * we[u]);
                acc.y = fmaxf(acc.y, v[u].y * we[u]);
                acc.z = fmaxf(acc.z, v[u].z * we[u]);
                acc.w = fmaxf(acc.w, v[u].w * we[u]);
            }
        }
        // tail
        for (; j < m; ++j) {
            int   s  = s_src[j];
            float we = s_w[j];
            const float4 v = *reinterpret_cast<const float4*>(Vbt + s * DD);
            acc.x = fmaxf(acc.x, v.x * we);
            acc.y = fmaxf(acc.y, v.y * we);
            acc.z = fmaxf(acc.z, v.z * we);
            acc.w = fmaxf(acc.w, v.w * we);
        }
        __syncthreads();
    }

    const float ninf = -__builtin_huge_valf();
    float4 r;
    r.x = (acc.x == ninf) ? 0.0f : acc.x;
    r.y = (acc.y == ninf) ? 0.0f : acc.y;
    r.z = (acc.z == ninf) ? 0.0f : acc.z;
    r.w = (acc.w == ninf) ? 0.0f : acc.w;
    *reinterpret_cast<float4*>(out + ((long)bt * NN + n) * DD + d4) = r;
}

// ---------------- launch ----------------

extern "C" void kernel_launch(void* const* d_in, const int* in_sizes, int n_in,
                              void* d_out, int out_size, void* d_ws, size_t ws_size,
                              hipStream_t stream) {
    const float* V   = (const float*)d_in[0];
    const int*   src = (const int*)d_in[1];
    const int*   dst = (const int*)d_in[2];
    const float* w   = (const float*)d_in[3];
    float* out = (float*)d_out;

    int* ws_i = (int*)d_ws;
    int*   counts  = ws_i;
    int*   offsets = ws_i + NN;
    int*   cursor  = ws_i + 2 * NN + 1;
    int*   esrc    = ws_i + 3 * NN + 1;
    float* ew      = (float*)(ws_i + 3 * NN + 1 + NE);

    k_zero<<<(NN + 255) / 256, 256, 0, stream>>>(counts);
    k_hist<<<(NE + 255) / 256, 256, 0, stream>>>(dst, counts);
    k_scan<<<1, SCAN_THREADS, 0, stream>>>(counts, offsets, cursor);
    k_scatter<<<(NE + 255) / 256, 256, 0, stream>>>(src, dst, w, cursor, esrc, ew);
    k_main<<<NN, 384, 0, stream>>>(V, offsets, esrc, ew, out);
}

// Round 4
// 137.476 us; speedup vs baseline: 32.9685x; 2.4107x over previous
//
#include <hip/hip_runtime.h>

// Problem constants: B=8, T=12 (BT=96), N=10000, D=16, E=160000
#define NN  10000
#define NE  160000
#define NBT 96
#define DD  16

#define SCAN_THREADS 1024
#define SCHUNK 10                 // ceil(NN / SCAN_THREADS)

#define NODES_PER_BLOCK 64
#define NCHUNK 157                // ceil(NN / NODES_PER_BLOCK)
#define NXCD 8
#define BT_PER_XCD 12             // NBT / NXCD

// ---------------- CSR build ----------------

__global__ void k_zero(int* __restrict__ counts) {
    int i = blockIdx.x * blockDim.x + threadIdx.x;
    if (i < NN) counts[i] = 0;
}

__global__ void k_hist(const int* __restrict__ dst, int* __restrict__ counts) {
    int e = blockIdx.x * blockDim.x + threadIdx.x;
    if (e < NE) atomicAdd(&counts[dst[e]], 1);
}

__global__ __launch_bounds__(SCAN_THREADS) void k_scan(const int* __restrict__ counts,
                                                       int* __restrict__ offsets,
                                                       int* __restrict__ cursor) {
    __shared__ int part[SCAN_THREADS];
    int tid = threadIdx.x;
    int begin = tid * SCHUNK;
    int end   = min(begin + SCHUNK, NN);
    int s = 0;
    for (int i = begin; i < end; ++i) s += counts[i];
    part[tid] = s;
    __syncthreads();
    for (int off = 1; off < SCAN_THREADS; off <<= 1) {
        int v = (tid >= off) ? part[tid - off] : 0;
        __syncthreads();
        part[tid] += v;
        __syncthreads();
    }
    int run = (tid == 0) ? 0 : part[tid - 1];
    for (int i = begin; i < end; ++i) {
        offsets[i] = run;
        cursor[i]  = run;
        run += counts[i];
    }
    if (tid == SCAN_THREADS - 1) offsets[NN] = part[SCAN_THREADS - 1];
}

__global__ void k_scatter(const int* __restrict__ src, const int* __restrict__ dst,
                          const float* __restrict__ w,
                          int* __restrict__ cursor,
                          int* __restrict__ esrc, float* __restrict__ ew) {
    int e = blockIdx.x * blockDim.x + threadIdx.x;
    if (e >= NE) return;
    int d = dst[e];
    int pos = atomicAdd(&cursor[d], 1);
    esrc[pos] = src[e];
    ew[pos]   = w[e];
}

// ---------------- main gather-max ----------------
// One block = (one bt slice, 64-node chunk). 256 threads = 64 nodes x 4 d4-slots.
// XCD pinning: idx%8 selects XCD (round-robin dispatch heuristic); each XCD owns
// bt in {r, r+8, ..., r+88} and walks all chunks of one bt before the next, so
// the 640 KB V-slice stays L2-resident.
__global__ __launch_bounds__(256) void k_main(const float* __restrict__ V,
                                              const int* __restrict__ offsets,
                                              const int* __restrict__ esrc,
                                              const float* __restrict__ ew,
                                              float* __restrict__ out) {
    int idx = blockIdx.x;
    int r   = idx & 7;
    int k   = idx >> 3;
    int btd = k / NCHUNK;             // 0..11
    int chunk = k - btd * NCHUNK;     // 0..156
    int bt  = r + 8 * btd;            // 0..95

    int tid = threadIdx.x;
    int n   = chunk * NODES_PER_BLOCK + (tid >> 2);
    int d4  = (tid & 3) << 2;
    if (n >= NN) return;              // no LDS/sync below: early-exit safe

    const float* __restrict__ Vs = V + (size_t)bt * (NN * DD) + d4;

    int beg  = offsets[n];
    int endo = offsets[n + 1];

    const float ninf = -__builtin_huge_valf();
    float4 acc;
    acc.x = acc.y = acc.z = acc.w = ninf;

    int j = beg;
    for (; j + 4 <= endo; j += 4) {
        int   s0 = esrc[j],   s1 = esrc[j+1], s2 = esrc[j+2], s3 = esrc[j+3];
        float w0 = ew[j],     w1 = ew[j+1],   w2 = ew[j+2],   w3 = ew[j+3];
        float4 v0 = *reinterpret_cast<const float4*>(Vs + s0 * DD);
        float4 v1 = *reinterpret_cast<const float4*>(Vs + s1 * DD);
        float4 v2 = *reinterpret_cast<const float4*>(Vs + s2 * DD);
        float4 v3 = *reinterpret_cast<const float4*>(Vs + s3 * DD);
        acc.x = fmaxf(acc.x, fmaxf(fmaxf(v0.x*w0, v1.x*w1), fmaxf(v2.x*w2, v3.x*w3)));
        acc.y = fmaxf(acc.y, fmaxf(fmaxf(v0.y*w0, v1.y*w1), fmaxf(v2.y*w2, v3.y*w3)));
        acc.z = fmaxf(acc.z, fmaxf(fmaxf(v0.z*w0, v1.z*w1), fmaxf(v2.z*w2, v3.z*w3)));
        acc.w = fmaxf(acc.w, fmaxf(fmaxf(v0.w*w0, v1.w*w1), fmaxf(v2.w*w2, v3.w*w3)));
    }
    for (; j < endo; ++j) {
        int   s  = esrc[j];
        float we = ew[j];
        float4 v = *reinterpret_cast<const float4*>(Vs + s * DD);
        acc.x = fmaxf(acc.x, v.x * we);
        acc.y = fmaxf(acc.y, v.y * we);
        acc.z = fmaxf(acc.z, v.z * we);
        acc.w = fmaxf(acc.w, v.w * we);
    }

    float4 rr;
    rr.x = (acc.x == ninf) ? 0.0f : acc.x;
    rr.y = (acc.y == ninf) ? 0.0f : acc.y;
    rr.z = (acc.z == ninf) ? 0.0f : acc.z;
    rr.w = (acc.w == ninf) ? 0.0f : acc.w;
    *reinterpret_cast<float4*>(out + ((size_t)bt * NN + n) * DD + d4) = rr;
}

// ---------------- launch ----------------

extern "C" void kernel_launch(void* const* d_in, const int* in_sizes, int n_in,
                              void* d_out, int out_size, void* d_ws, size_t ws_size,
                              hipStream_t stream) {
    const float* V   = (const float*)d_in[0];
    const int*   src = (const int*)d_in[1];
    const int*   dst = (const int*)d_in[2];
    const float* w   = (const float*)d_in[3];
    float* out = (float*)d_out;

    int* ws_i = (int*)d_ws;
    int*   counts  = ws_i;
    int*   offsets = ws_i + NN;
    int*   cursor  = ws_i + 2 * NN + 1;
    int*   esrc    = ws_i + 3 * NN + 1;
    float* ew      = (float*)(ws_i + 3 * NN + 1 + NE);

    k_zero<<<(NN + 255) / 256, 256, 0, stream>>>(counts);
    k_hist<<<(NE + 255) / 256, 256, 0, stream>>>(dst, counts);
    k_scan<<<1, SCAN_THREADS, 0, stream>>>(counts, offsets, cursor);
    k_scatter<<<(NE + 255) / 256, 256, 0, stream>>>(src, dst, w, cursor, esrc, ew);

    int nblocks = NXCD * BT_PER_XCD * NCHUNK;   // 15072
    k_main<<<nblocks, 256, 0, stream>>>(V, offsets, esrc, ew, out);
}